// Round 14
// baseline (76.886 us; speedup 1.0000x reference)
//
#include <hip/hip_runtime.h>

#define B_ 2048
#define S_ 512
#define T_ 17
#define RECN 288
#define FWDW 448          // 7 segments x 64 waves (fwd F0..F6)
#define MAINW 896         // + 7 segments x 64 waves (bwd G1..G7)

typedef float v16f __attribute__((ext_vector_type(16)));
typedef short v8s  __attribute__((ext_vector_type(8)));
typedef float f4u  __attribute__((ext_vector_type(4), aligned(4)));

union frag_u { unsigned u[4]; v8s v; };

static __device__ inline unsigned pkbf(float lo, float hi) {
    unsigned r;
    asm("v_cvt_pk_bf16_f32 %0, %1, %2" : "=v"(r) : "v"(lo), "v"(hi));
    return r;
}

#define PACKB(S0,S1,S2,S3,S4,S5,S6,S7, BOUT) do {                            \
    unsigned P0_ = pkbf(S0, S1), P1_ = pkbf(S2, S3);                         \
    unsigned R0_ = pkbf(S4, S5), R1_ = pkbf(S6, S7);                         \
    auto s0_ = __builtin_amdgcn_permlane32_swap(P0_, R0_, false, false);     \
    auto s1_ = __builtin_amdgcn_permlane32_swap(P1_, R1_, false, false);     \
    BOUT.u[0] = s0_[0]; BOUT.u[1] = s1_[0];                                  \
    BOUT.u[2] = s0_[1]; BOUT.u[3] = s1_[1];                                  \
} while (0)

#define W16SWAP() do {                                                       \
    auto rw_ = __builtin_amdgcn_permlane32_swap(__float_as_uint(W8),         \
                                                __float_as_uint(W8),         \
                                                false, false);               \
    w16 = __uint_as_float(rw_[0]);                                           \
} while (0)

// ---- load one 8-row chunk: logits, masks, tags, boundary tag ----
#define LOADK8(Q0, Q1, SS, MA, MB, TGa, TPM1, T0_) do {                      \
    const float* bp_ = ip + (size_t)(T0_) * T_;                              \
    _Pragma("unroll") for (int u_ = 0; u_ < 8; ++u_) {                       \
        Q0[u_] = *(const f4u*)(bp_ + u_ * T_ + 4 * h);                       \
        Q1[u_] = *(const f4u*)(bp_ + u_ * T_ + 8 + 4 * h);                   \
        SS[u_] = bp_[u_ * T_ + 16];                                          \
    }                                                                        \
    MA = *(const int4*)(mp + (T0_));                                         \
    MB = *(const int4*)(mp + (T0_) + 4);                                     \
    { int4 ta_ = *(const int4*)(tp + (T0_));                                 \
      int4 tb_ = *(const int4*)(tp + (T0_) + 4);                             \
      TGa[0]=ta_.x; TGa[1]=ta_.y; TGa[2]=ta_.z; TGa[3]=ta_.w;                \
      TGa[4]=tb_.x; TGa[5]=tb_.y; TGa[6]=tb_.z; TGa[7]=tb_.w; }              \
    TPM1 = tp[(T0_) > 0 ? (T0_) - 1 : 0];                                    \
} while (0)

// ---- fused path-score accumulation for one 8-row chunk (off-chain) ----
#define SCORE8(Q0a, Q1a, Sa, TGa, MA, MB, TPM1, T0_) do {                    \
    if (own) {                                                               \
        int pt_ = (TPM1);                                                    \
        int mv_[8] = {(MA).x,(MA).y,(MA).z,(MA).w,                           \
                      (MB).x,(MB).y,(MB).z,(MB).w};                          \
        _Pragma("unroll") for (int u_ = 0; u_ < 8; ++u_) {                   \
            const int t_ = (T0_) + u_;                                       \
            const int tg_ = TGa[u_];                                         \
            const float mf_ = (float)mv_[u_];                                \
            f4u q0_ = Q0a[u_], q1_ = Q1a[u_];                                \
            float ev_ = (tg_==4*h+0)?q0_.x:(tg_==4*h+1)?q0_.y:               \
                        (tg_==4*h+2)?q0_.z:(tg_==4*h+3)?q0_.w:               \
                        (tg_==8+4*h+0)?q1_.x:(tg_==8+4*h+1)?q1_.y:           \
                        (tg_==8+4*h+2)?q1_.z:(tg_==8+4*h+3)?q1_.w:           \
                        ((h==0)&&(tg_==16))?Sa[u_]:0.0f;                     \
            acc_e = fmaf((t_ <= S_-2)?mf_:0.0f, ev_, acc_e);                 \
            if (h == 0) {                                                    \
                float tv_ = tl[pt_*T_ + tg_];                                \
                acc_tr = fmaf((t_>=1)?mf_:0.0f, tv_, acc_tr);                \
                msum += mv_[u_];                                             \
            }                                                                \
            pt_ = tg_;                                                       \
        }                                                                    \
    }                                                                        \
} while (0)

#define FSTEP(Q0u, Q1u, Su, Mu) do {                                         \
    frag_u Bf_;                                                              \
    PACKB(W0,W1,W2,W3,W4,W5,W6,W7, Bf_);                                     \
    v16f acc_ = __builtin_amdgcn_mfma_f32_32x32x16_bf16(A1.v, Bf_.v, zacc,0,0,0); \
    float d0_=__expf((Q0u).x), d1_=__expf((Q0u).y);                          \
    float d2_=__expf((Q0u).z), d3_=__expf((Q0u).w);                          \
    float d4_=__expf((Q1u).x), d5_=__expf((Q1u).y);                          \
    float d6_=__expf((Q1u).z), d7_=__expf((Q1u).w);                          \
    float d8_=__expf(Su);                                                    \
    bool bm_ = (Mu) != 0;                                                    \
    float n0_ = fmaf(E16[0], w16, acc_[0]) * d0_;                            \
    float n1_ = fmaf(E16[1], w16, acc_[1]) * d1_;                            \
    float n2_ = fmaf(E16[2], w16, acc_[2]) * d2_;                            \
    float n3_ = fmaf(E16[3], w16, acc_[3]) * d3_;                            \
    float n4_ = fmaf(E16[4], w16, acc_[4]) * d4_;                            \
    float n5_ = fmaf(E16[5], w16, acc_[5]) * d5_;                            \
    float n6_ = fmaf(E16[6], w16, acc_[6]) * d6_;                            \
    float n7_ = fmaf(E16[7], w16, acc_[7]) * d7_;                            \
    float n8_ = fmaf(E16[8], w16, acc_[8]) * d8_;                            \
    W0=bm_?n0_:W0; W1=bm_?n1_:W1; W2=bm_?n2_:W2; W3=bm_?n3_:W3;              \
    W4=bm_?n4_:W4; W5=bm_?n5_:W5; W6=bm_?n6_:W6; W7=bm_?n7_:W7;              \
    W8=bm_?n8_:W8;                                                           \
    W16SWAP();                                                               \
} while (0)

#define BSTEP(Q0u, Q1u, Su, Mu) do {                                         \
    float d0_=__expf((Q0u).x), d1_=__expf((Q0u).y);                          \
    float d2_=__expf((Q0u).z), d3_=__expf((Q0u).w);                          \
    float d4_=__expf((Q1u).x), d5_=__expf((Q1u).y);                          \
    float d6_=__expf((Q1u).z), d7_=__expf((Q1u).w);                          \
    float d8_=__expf(Su);                                                    \
    float U16_ = w16 * d8_;                                                  \
    frag_u Bf_;                                                              \
    PACKB(W0*d0_, W1*d1_, W2*d2_, W3*d3_,                                    \
          W4*d4_, W5*d5_, W6*d6_, W7*d7_, Bf_);                              \
    v16f acc_ = __builtin_amdgcn_mfma_f32_32x32x16_bf16(A1.v, Bf_.v, zacc,0,0,0); \
    bool bm_ = (Mu) != 0;                                                    \
    float n0_ = fmaf(E16[0], U16_, acc_[0]);                                 \
    float n1_ = fmaf(E16[1], U16_, acc_[1]);                                 \
    float n2_ = fmaf(E16[2], U16_, acc_[2]);                                 \
    float n3_ = fmaf(E16[3], U16_, acc_[3]);                                 \
    float n4_ = fmaf(E16[4], U16_, acc_[4]);                                 \
    float n5_ = fmaf(E16[5], U16_, acc_[5]);                                 \
    float n6_ = fmaf(E16[6], U16_, acc_[6]);                                 \
    float n7_ = fmaf(E16[7], U16_, acc_[7]);                                 \
    float n8_ = fmaf(E16[8], U16_, acc_[8]);                                 \
    W0=bm_?n0_:W0; W1=bm_?n1_:W1; W2=bm_?n2_:W2; W3=bm_?n3_:W3;              \
    W4=bm_?n4_:W4; W5=bm_?n5_:W5; W6=bm_?n6_:W6; W7=bm_?n7_:W7;              \
    W8=bm_?n8_:W8;                                                           \
    W16SWAP();                                                               \
} while (0)

#define RENORM() do {                                                        \
    float M_ = fmaxf(fmaxf(fmaxf(W0,W1),fmaxf(W2,W3)),                       \
                     fmaxf(fmaxf(W4,W5),fmaxf(fmaxf(W6,W7),W8)));            \
    auto rm_ = __builtin_amdgcn_permlane32_swap(__float_as_uint(M_),         \
                                                __float_as_uint(M_),         \
                                                false, false);               \
    M_ = fmaxf(__uint_as_float(rm_[0]), __uint_as_float(rm_[1]));            \
    float r_ = 1.0f / M_;                                                    \
    Z += __logf(M_);                                                         \
    W0*=r_; W1*=r_; W2*=r_; W3*=r_; W4*=r_;                                  \
    W5*=r_; W6*=r_; W7*=r_; W8*=r_; w16*=r_;                                 \
} while (0)

#define FCH8(Q0a, Q1a, Sa, Ma, Mb) do {                                      \
    FSTEP(Q0a[0], Q1a[0], Sa[0], (Ma).x);                                    \
    FSTEP(Q0a[1], Q1a[1], Sa[1], (Ma).y);                                    \
    FSTEP(Q0a[2], Q1a[2], Sa[2], (Ma).z);                                    \
    FSTEP(Q0a[3], Q1a[3], Sa[3], (Ma).w);                                    \
    RENORM();                                                                \
    FSTEP(Q0a[4], Q1a[4], Sa[4], (Mb).x);                                    \
    FSTEP(Q0a[5], Q1a[5], Sa[5], (Mb).y);                                    \
    FSTEP(Q0a[6], Q1a[6], Sa[6], (Mb).z);                                    \
    FSTEP(Q0a[7], Q1a[7], Sa[7], (Mb).w);                                    \
    RENORM();                                                                \
} while (0)

#define BCH8(Q0a, Q1a, Sa, Ma, Mb) do {                                      \
    BSTEP(Q0a[7], Q1a[7], Sa[7], (Mb).w);                                    \
    BSTEP(Q0a[6], Q1a[6], Sa[6], (Mb).z);                                    \
    BSTEP(Q0a[5], Q1a[5], Sa[5], (Mb).y);                                    \
    BSTEP(Q0a[4], Q1a[4], Sa[4], (Mb).x);                                    \
    RENORM();                                                                \
    BSTEP(Q0a[3], Q1a[3], Sa[3], (Ma).w);                                    \
    BSTEP(Q0a[2], Q1a[2], Sa[2], (Ma).z);                                    \
    BSTEP(Q0a[1], Q1a[1], Sa[1], (Ma).y);                                    \
    BSTEP(Q0a[0], Q1a[0], Sa[0], (Ma).x);                                    \
    RENORM();                                                                \
} while (0)

__global__ __launch_bounds__(64) void crf_seg(
    const float* __restrict__ inputs, const int* __restrict__ tags,
    const int* __restrict__ mask, const float* __restrict__ trans,
    const float* __restrict__ startt, const float* __restrict__ endt,
    float* __restrict__ ws)
{
    __shared__ float tl[T_ * T_];
    const int lane = (int)threadIdx.x;
    const int bid = (int)blockIdx.x;
    for (int k = lane; k < T_ * T_; k += 64) tl[k] = trans[k];
    __syncthreads();

    const bool isF = (bid < FWDW);
    const int widx = isF ? bid : bid - FWDW;
    const int j = widx >> 6;              // fwd: seg 0..6 ; bwd: seg j+1
    const int sg = widx & 63;
    const int h = lane >> 5;
    const int col = lane & 31;
    const int seq = sg * 32 + col;
    const int jb = j + 1;                 // bwd segment id
    const bool own = isF ? (j <= 3) : (jb >= 4);

    frag_u A1;
#pragma unroll
    for (int wd = 0; wd < 4; ++wd) {
        const int k0 = 8 * h + 2 * wd, k1 = k0 + 1;
        float e0 = 0.0f, e1 = 0.0f;
        if (col < 17) {
            e0 = isF ? __expf(tl[k0 * T_ + col]) : __expf(tl[col * T_ + k0]);
            e1 = isF ? __expf(tl[k1 * T_ + col]) : __expf(tl[col * T_ + k1]);
        }
        A1.u[wd] = pkbf(e0, e1);
    }
    float E16[9];
#pragma unroll
    for (int k = 0; k < 4; ++k) {
        const int r0 = 4 * h + k, r1 = 8 + 4 * h + k;
        E16[k]     = __expf(isF ? tl[16 * T_ + r0] : tl[r0 * T_ + 16]);
        E16[4 + k] = __expf(isF ? tl[16 * T_ + r1] : tl[r1 * T_ + 16]);
    }
    E16[8] = (h == 0) ? __expf(tl[16 * T_ + 16]) : 0.0f;

    v16f zacc;
#pragma unroll
    for (int r = 0; r < 16; ++r) zacc[r] = 0.0f;

    const float* ip = inputs + (size_t)seq * (S_ * T_);
    const int*   mp = mask + (size_t)seq * S_;
    const int*   tp = tags + (size_t)seq * S_;

    float W0, W1, W2, W3, W4, W5, W6, W7, W8, w16, Z = 0.0f;
    float acc_e = 0.0f, acc_tr = 0.0f;
    int msum = 0;
    f4u X0[8], X1[8]; float XS[8]; int4 XM0, XM1; int XT[8]; int XTP;
    f4u Y0[8], Y1[8]; float YS[8]; int4 YM0, YM1; int YT[8]; int YTP;

    int off;
    if (isF) {
        if (j == 0) {
            // F0: exact fwd from alpha0, steps t=1..63
            LOADK8(X0, X1, XS, XM0, XM1, XT, XTP, 0);
            LOADK8(Y0, Y1, YS, YM0, YM1, YT, YTP, 8);
            f4u s0 = *(const f4u*)(startt + 4 * h);
            f4u s1 = *(const f4u*)(startt + 8 + 4 * h);
            W0 = __expf(X0[0].x + s0.x); W1 = __expf(X0[0].y + s0.y);
            W2 = __expf(X0[0].z + s0.z); W3 = __expf(X0[0].w + s0.w);
            W4 = __expf(X1[0].x + s1.x); W5 = __expf(X1[0].y + s1.y);
            W6 = __expf(X1[0].z + s1.z); W7 = __expf(X1[0].w + s1.w);
            W8 = h ? 0.0f : __expf(XS[0] + startt[16]);
            W16SWAP();
            FSTEP(X0[1], X1[1], XS[1], XM0.y);
            FSTEP(X0[2], X1[2], XS[2], XM0.z);
            FSTEP(X0[3], X1[3], XS[3], XM0.w);
            RENORM();
            FSTEP(X0[4], X1[4], XS[4], XM1.x);
            FSTEP(X0[5], X1[5], XS[5], XM1.y);
            FSTEP(X0[6], X1[6], XS[6], XM1.z);
            FSTEP(X0[7], X1[7], XS[7], XM1.w);
            RENORM();
            SCORE8(X0, X1, XS, XT, XM0, XM1, XTP, 0);
            for (int c = 0; c < 3; ++c) {
                LOADK8(X0, X1, XS, XM0, XM1, XT, XTP, 16 + 16 * c);
                FCH8(Y0, Y1, YS, YM0, YM1);
                SCORE8(Y0, Y1, YS, YT, YM0, YM1, YTP, 8 + 16 * c);
                LOADK8(Y0, Y1, YS, YM0, YM1, YT, YTP, 24 + 16 * c);
                FCH8(X0, X1, XS, XM0, XM1);
                SCORE8(X0, X1, XS, XT, XM0, XM1, XTP, 16 + 16 * c);
            }
            FCH8(Y0, Y1, YS, YM0, YM1);
            SCORE8(Y0, Y1, YS, YT, YM0, YM1, YTP, 56);
        } else {
            // Fj: fwd from ones, steps t=64j..64j+63
            const int tb = 64 * j;
            LOADK8(X0, X1, XS, XM0, XM1, XT, XTP, tb);
            LOADK8(Y0, Y1, YS, YM0, YM1, YT, YTP, tb + 8);
            W0=W1=W2=W3=W4=W5=W6=W7 = 1.0f;
            W8 = h ? 0.0f : 1.0f;
            W16SWAP();
            for (int c = 0; c < 3; ++c) {
                FCH8(X0, X1, XS, XM0, XM1);
                SCORE8(X0, X1, XS, XT, XM0, XM1, XTP, tb + 16 * c);
                LOADK8(X0, X1, XS, XM0, XM1, XT, XTP, tb + 16 + 16 * c);
                FCH8(Y0, Y1, YS, YM0, YM1);
                SCORE8(Y0, Y1, YS, YT, YM0, YM1, YTP, tb + 8 + 16 * c);
                LOADK8(Y0, Y1, YS, YM0, YM1, YT, YTP, tb + 24 + 16 * c);
            }
            FCH8(X0, X1, XS, XM0, XM1);
            SCORE8(X0, X1, XS, XT, XM0, XM1, XTP, tb + 48);
            FCH8(Y0, Y1, YS, YM0, YM1);
            SCORE8(Y0, Y1, YS, YT, YM0, YM1, YTP, tb + 56);
        }
        off = j * 18;
    } else {
        // Gjb: transpose run, steps t=64jb+63 .. 64jb
        const int tb = 64 * jb;
        LOADK8(X0, X1, XS, XM0, XM1, XT, XTP, tb + 56);
        LOADK8(Y0, Y1, YS, YM0, YM1, YT, YTP, tb + 48);
        if (jb == 7) {
            f4u e0 = *(const f4u*)(endt + 4 * h);
            f4u e1 = *(const f4u*)(endt + 8 + 4 * h);
            W0 = __expf(e0.x); W1 = __expf(e0.y);
            W2 = __expf(e0.z); W3 = __expf(e0.w);
            W4 = __expf(e1.x); W5 = __expf(e1.y);
            W6 = __expf(e1.z); W7 = __expf(e1.w);
            W8 = h ? 0.0f : __expf(endt[16]);
        } else {
            W0=W1=W2=W3=W4=W5=W6=W7 = 1.0f;
            W8 = h ? 0.0f : 1.0f;
        }
        W16SWAP();
        for (int c = 0; c < 3; ++c) {
            BCH8(X0, X1, XS, XM0, XM1);
            SCORE8(X0, X1, XS, XT, XM0, XM1, XTP, tb + 56 - 16 * c);
            LOADK8(X0, X1, XS, XM0, XM1, XT, XTP, tb + 40 - 16 * c);
            BCH8(Y0, Y1, YS, YM0, YM1);
            SCORE8(Y0, Y1, YS, YT, YM0, YM1, YTP, tb + 48 - 16 * c);
            LOADK8(Y0, Y1, YS, YM0, YM1, YT, YTP, tb + 32 - 16 * c);
        }
        BCH8(X0, X1, XS, XM0, XM1);
        SCORE8(X0, X1, XS, XT, XM0, XM1, XTP, tb + 8);
        BCH8(Y0, Y1, YS, YM0, YM1);
        SCORE8(Y0, Y1, YS, YT, YM0, YM1, YTP, tb + 0);
        off = 126 + (jb - 1) * 18;
    }

    float* rec = ws + (size_t)seq * RECN + off;
    rec[4*h+0] = W0; rec[4*h+1] = W1; rec[4*h+2] = W2; rec[4*h+3] = W3;
    rec[8+4*h+0] = W4; rec[8+4*h+1] = W5; rec[8+4*h+2] = W6; rec[8+4*h+3] = W7;
    if (h == 0) { rec[16] = W8; rec[17] = Z; }

    if (own) {
        auto re_ = __builtin_amdgcn_permlane32_swap(__float_as_uint(acc_e),
                                                    __float_as_uint(acc_e),
                                                    false, false);
        float etot = acc_e + __uint_as_float(re_[1]);   // h0: own + partner
        if (h == 0) {
            const int soff = isF ? (252 + 3 * j) : (264 + 3 * (jb - 4));
            float* sr = ws + (size_t)seq * RECN + soff;
            sr[0] = etot; sr[1] = acc_tr; sr[2] = (float)msum;
        }
    }
}

// ---- combine: one thread per sequence ----
__global__ __launch_bounds__(256) void crf_comb(
    const float* __restrict__ recs, const float* __restrict__ inputs,
    const int* __restrict__ tags, const int* __restrict__ mask,
    const float* __restrict__ startt, const float* __restrict__ endt,
    float* __restrict__ partial)
{
    __shared__ float sm[256];
    const int tid = (int)threadIdx.x;
    const int s = (int)blockIdx.x * 256 + tid;

    float a = 0.0f;
    {
        const float* r = recs + (size_t)s * RECN;
        float zsum = r[17];               // ZF0
        float logn = 0.0f;
#pragma unroll
        for (int j = 1; j <= 7; ++j) {
            const float* G = r + 126 + (j - 1) * 18;
            const float* F = r + (j - 1) * 18;
            float dot = 0.0f;
#pragma unroll
            for (int i = 0; i < T_; ++i) dot = fmaf(G[i], F[i], dot);
            logn += __logf(dot);
            zsum += G[17];
        }
#pragma unroll
        for (int j = 1; j <= 6; ++j) {
            const float* F = r + j * 18;
            float sf = 0.0f;
#pragma unroll
            for (int i = 0; i < T_; ++i) sf += F[i];
            logn -= __logf(sf);
        }
        // path score from the 8 owner-wave partials
        float e = 0.0f, tr = 0.0f, msf = 0.0f;
#pragma unroll
        for (int k = 0; k < 8; ++k) {
            e   += r[252 + 3 * k];
            tr  += r[253 + 3 * k];
            msf += r[254 + 3 * k];
        }
        int ms = (int)(msf + 0.5f);
        int li = ms - 1; if (li < 0) li = 0;
        int lt = tags[(size_t)s * S_ + li];
        float ml = (float)mask[(size_t)s * S_ + (S_ - 1)];
        float lin = inputs[((size_t)s * S_ + (S_ - 1)) * T_ + lt];
        float sc = startt[tags[(size_t)s * S_]] + tr + e + endt[lt] + lin * ml;
        a = sc - (logn + zsum);
    }
    sm[tid] = a;
    __syncthreads();
    for (int k = 128; k >= 1; k >>= 1) {
        if (tid < k) sm[tid] += sm[tid + k];
        __syncthreads();
    }
    if (tid == 0) partial[blockIdx.x] = sm[0];
}

__global__ __launch_bounds__(64) void crf_red(const float* __restrict__ partial,
                                              float* __restrict__ out)
{
    if (threadIdx.x == 0) {
        float s = 0.0f;
#pragma unroll
        for (int i = 0; i < 8; ++i) s += partial[i];
        out[0] = s;
    }
}

extern "C" void kernel_launch(void* const* d_in, const int* in_sizes, int n_in,
                              void* d_out, int out_size, void* d_ws, size_t ws_size,
                              hipStream_t stream)
{
    const float* inputs = (const float*)d_in[0];
    const int*   tags   = (const int*)d_in[1];
    const int*   mask   = (const int*)d_in[2];
    const float* trans  = (const float*)d_in[3];
    const float* startt = (const float*)d_in[4];
    const float* endt   = (const float*)d_in[5];
    float* out = (float*)d_out;
    float* ws  = (float*)d_ws;
    float* partial = ws + (size_t)B_ * RECN;

    crf_seg<<<MAINW, 64, 0, stream>>>(inputs, tags, mask, trans,
                                      startt, endt, ws);
    crf_comb<<<B_ / 256, 256, 0, stream>>>(ws, inputs, tags, mask,
                                           startt, endt, partial);
    crf_red<<<1, 64, 0, stream>>>(partial, out);
}

// Round 15
// 70.344 us; speedup vs baseline: 1.0930x; 1.0930x over previous
//
#include <hip/hip_runtime.h>

#define B_ 2048
#define S_ 512
#define T_ 17
#define NSEG 16
#define LSEG 32
#define RECN 544
#define FWDW 960          // 15 segments x 64 waves (fwd F0..F14)
#define MAINW 1920        // + 15 segments x 64 waves (bwd G1..G15)
#define GB 270            // G-record base: 15*18

typedef float v16f __attribute__((ext_vector_type(16)));
typedef short v8s  __attribute__((ext_vector_type(8)));
typedef float f4u  __attribute__((ext_vector_type(4), aligned(4)));

union frag_u { unsigned u[4]; v8s v; };

static __device__ inline unsigned pkbf(float lo, float hi) {
    unsigned r;
    asm("v_cvt_pk_bf16_f32 %0, %1, %2" : "=v"(r) : "v"(lo), "v"(hi));
    return r;
}

#define PACKB(S0,S1,S2,S3,S4,S5,S6,S7, BOUT) do {                            \
    unsigned P0_ = pkbf(S0, S1), P1_ = pkbf(S2, S3);                         \
    unsigned R0_ = pkbf(S4, S5), R1_ = pkbf(S6, S7);                         \
    auto s0_ = __builtin_amdgcn_permlane32_swap(P0_, R0_, false, false);     \
    auto s1_ = __builtin_amdgcn_permlane32_swap(P1_, R1_, false, false);     \
    BOUT.u[0] = s0_[0]; BOUT.u[1] = s1_[0];                                  \
    BOUT.u[2] = s0_[1]; BOUT.u[3] = s1_[1];                                  \
} while (0)

#define W16SWAP() do {                                                       \
    auto rw_ = __builtin_amdgcn_permlane32_swap(__float_as_uint(W8),         \
                                                __float_as_uint(W8),         \
                                                false, false);               \
    w16 = __uint_as_float(rw_[0]);                                           \
} while (0)

#define LOADK8(Q0, Q1, SS, MA, MB, T0_) do {                                 \
    const float* bp_ = ip + (size_t)(T0_) * T_;                              \
    _Pragma("unroll") for (int u_ = 0; u_ < 8; ++u_) {                       \
        Q0[u_] = *(const f4u*)(bp_ + u_ * T_ + 4 * h);                       \
        Q1[u_] = *(const f4u*)(bp_ + u_ * T_ + 8 + 4 * h);                   \
        SS[u_] = bp_[u_ * T_ + 16];                                          \
    }                                                                        \
    MA = *(const int4*)(mp + (T0_));                                         \
    MB = *(const int4*)(mp + (T0_) + 4);                                     \
} while (0)

#define FSTEP(Q0u, Q1u, Su, Mu) do {                                         \
    frag_u Bf_;                                                              \
    PACKB(W0,W1,W2,W3,W4,W5,W6,W7, Bf_);                                     \
    v16f acc_ = __builtin_amdgcn_mfma_f32_32x32x16_bf16(A1.v, Bf_.v, zacc,0,0,0); \
    float d0_=__expf((Q0u).x), d1_=__expf((Q0u).y);                          \
    float d2_=__expf((Q0u).z), d3_=__expf((Q0u).w);                          \
    float d4_=__expf((Q1u).x), d5_=__expf((Q1u).y);                          \
    float d6_=__expf((Q1u).z), d7_=__expf((Q1u).w);                          \
    float d8_=__expf(Su);                                                    \
    bool bm_ = (Mu) != 0;                                                    \
    float n0_ = fmaf(E16[0], w16, acc_[0]) * d0_;                            \
    float n1_ = fmaf(E16[1], w16, acc_[1]) * d1_;                            \
    float n2_ = fmaf(E16[2], w16, acc_[2]) * d2_;                            \
    float n3_ = fmaf(E16[3], w16, acc_[3]) * d3_;                            \
    float n4_ = fmaf(E16[4], w16, acc_[4]) * d4_;                            \
    float n5_ = fmaf(E16[5], w16, acc_[5]) * d5_;                            \
    float n6_ = fmaf(E16[6], w16, acc_[6]) * d6_;                            \
    float n7_ = fmaf(E16[7], w16, acc_[7]) * d7_;                            \
    float n8_ = fmaf(E16[8], w16, acc_[8]) * d8_;                            \
    W0=bm_?n0_:W0; W1=bm_?n1_:W1; W2=bm_?n2_:W2; W3=bm_?n3_:W3;              \
    W4=bm_?n4_:W4; W5=bm_?n5_:W5; W6=bm_?n6_:W6; W7=bm_?n7_:W7;              \
    W8=bm_?n8_:W8;                                                           \
    W16SWAP();                                                               \
} while (0)

#define BSTEP(Q0u, Q1u, Su, Mu) do {                                         \
    float d0_=__expf((Q0u).x), d1_=__expf((Q0u).y);                          \
    float d2_=__expf((Q0u).z), d3_=__expf((Q0u).w);                          \
    float d4_=__expf((Q1u).x), d5_=__expf((Q1u).y);                          \
    float d6_=__expf((Q1u).z), d7_=__expf((Q1u).w);                          \
    float d8_=__expf(Su);                                                    \
    float U16_ = w16 * d8_;                                                  \
    frag_u Bf_;                                                              \
    PACKB(W0*d0_, W1*d1_, W2*d2_, W3*d3_,                                    \
          W4*d4_, W5*d5_, W6*d6_, W7*d7_, Bf_);                              \
    v16f acc_ = __builtin_amdgcn_mfma_f32_32x32x16_bf16(A1.v, Bf_.v, zacc,0,0,0); \
    bool bm_ = (Mu) != 0;                                                    \
    float n0_ = fmaf(E16[0], U16_, acc_[0]);                                 \
    float n1_ = fmaf(E16[1], U16_, acc_[1]);                                 \
    float n2_ = fmaf(E16[2], U16_, acc_[2]);                                 \
    float n3_ = fmaf(E16[3], U16_, acc_[3]);                                 \
    float n4_ = fmaf(E16[4], U16_, acc_[4]);                                 \
    float n5_ = fmaf(E16[5], U16_, acc_[5]);                                 \
    float n6_ = fmaf(E16[6], U16_, acc_[6]);                                 \
    float n7_ = fmaf(E16[7], U16_, acc_[7]);                                 \
    float n8_ = fmaf(E16[8], U16_, acc_[8]);                                 \
    W0=bm_?n0_:W0; W1=bm_?n1_:W1; W2=bm_?n2_:W2; W3=bm_?n3_:W3;              \
    W4=bm_?n4_:W4; W5=bm_?n5_:W5; W6=bm_?n6_:W6; W7=bm_?n7_:W7;              \
    W8=bm_?n8_:W8;                                                           \
    W16SWAP();                                                               \
} while (0)

#define RENORM() do {                                                        \
    float M_ = fmaxf(fmaxf(fmaxf(W0,W1),fmaxf(W2,W3)),                       \
                     fmaxf(fmaxf(W4,W5),fmaxf(fmaxf(W6,W7),W8)));            \
    auto rm_ = __builtin_amdgcn_permlane32_swap(__float_as_uint(M_),         \
                                                __float_as_uint(M_),         \
                                                false, false);               \
    M_ = fmaxf(__uint_as_float(rm_[0]), __uint_as_float(rm_[1]));            \
    float r_ = 1.0f / M_;                                                    \
    Z += __logf(M_);                                                         \
    W0*=r_; W1*=r_; W2*=r_; W3*=r_; W4*=r_;                                  \
    W5*=r_; W6*=r_; W7*=r_; W8*=r_; w16*=r_;                                 \
} while (0)

#define FCH8(Q0a, Q1a, Sa, Ma, Mb) do {                                      \
    FSTEP(Q0a[0], Q1a[0], Sa[0], (Ma).x);                                    \
    FSTEP(Q0a[1], Q1a[1], Sa[1], (Ma).y);                                    \
    FSTEP(Q0a[2], Q1a[2], Sa[2], (Ma).z);                                    \
    FSTEP(Q0a[3], Q1a[3], Sa[3], (Ma).w);                                    \
    RENORM();                                                                \
    FSTEP(Q0a[4], Q1a[4], Sa[4], (Mb).x);                                    \
    FSTEP(Q0a[5], Q1a[5], Sa[5], (Mb).y);                                    \
    FSTEP(Q0a[6], Q1a[6], Sa[6], (Mb).z);                                    \
    FSTEP(Q0a[7], Q1a[7], Sa[7], (Mb).w);                                    \
    RENORM();                                                                \
} while (0)

#define BCH8(Q0a, Q1a, Sa, Ma, Mb) do {                                      \
    BSTEP(Q0a[7], Q1a[7], Sa[7], (Mb).w);                                    \
    BSTEP(Q0a[6], Q1a[6], Sa[6], (Mb).z);                                    \
    BSTEP(Q0a[5], Q1a[5], Sa[5], (Mb).y);                                    \
    BSTEP(Q0a[4], Q1a[4], Sa[4], (Mb).x);                                    \
    RENORM();                                                                \
    BSTEP(Q0a[3], Q1a[3], Sa[3], (Ma).w);                                    \
    BSTEP(Q0a[2], Q1a[2], Sa[2], (Ma).z);                                    \
    BSTEP(Q0a[1], Q1a[1], Sa[1], (Ma).y);                                    \
    BSTEP(Q0a[0], Q1a[0], Sa[0], (Ma).x);                                    \
    RENORM();                                                                \
} while (0)

static __device__ void helper_score(int s, int lane,
                                    const int* __restrict__ tags,
                                    const int* __restrict__ mask,
                                    const float* __restrict__ inputs,
                                    const float* __restrict__ startt,
                                    const float* __restrict__ endt,
                                    const float* tl, float* recs)
{
    const int* tp = tags + (size_t)s * S_;
    const int* mp = mask + (size_t)s * S_;
    const float* ib = inputs + (size_t)s * (S_ * T_);
    const int4* tp4 = (const int4*)tp;
    const int4* mp4 = (const int4*)mp;

    int4 t0 = tp4[2 * lane], t1 = tp4[2 * lane + 1];
    int4 m0 = mp4[2 * lane], m1 = mp4[2 * lane + 1];
    int tg[8] = {t0.x, t0.y, t0.z, t0.w, t1.x, t1.y, t1.z, t1.w};
    int mi[8] = {m0.x, m0.y, m0.z, m0.w, m1.x, m1.y, m1.z, m1.w};
    int tprev = (lane > 0) ? tp[8 * lane - 1] : 0;

    float e = 0.0f, tr = 0.0f;
    int ms = 0;
#pragma unroll
    for (int u = 0; u < 8; ++u) {
        int t = 8 * lane + u;
        float mf = (float)mi[u];
        float gate = (t <= S_ - 2) ? mf : 0.0f;
        e = fmaf(gate, ib[(size_t)t * T_ + tg[u]], e);
        int pt = (u == 0) ? tprev : tg[u - 1];
        float tv = tl[pt * T_ + tg[u]];
        tr = fmaf((t >= 1) ? mf : 0.0f, tv, tr);
        ms += mi[u];
    }
    for (int d = 1; d < 64; d <<= 1) {
        e  += __shfl_xor(e, d);
        tr += __shfl_xor(tr, d);
        ms += __shfl_xor(ms, d);
    }
    if (lane == 0) {
        int li = ms - 1; if (li < 0) li = 0;
        int lt = tp[li];
        float ml = (float)mp[S_ - 1];
        float lin = ib[(size_t)(S_ - 1) * T_ + lt];
        float sc = startt[tp[0]] + tr + e + endt[lt] + lin * ml;
        recs[(size_t)s * RECN + 540] = sc;
    }
}

__global__ __launch_bounds__(64) void crf_seg(
    const float* __restrict__ inputs, const int* __restrict__ tags,
    const int* __restrict__ mask, const float* __restrict__ trans,
    const float* __restrict__ startt, const float* __restrict__ endt,
    float* __restrict__ ws)
{
    __shared__ float tl[T_ * T_];
    const int lane = (int)threadIdx.x;
    const int bid = (int)blockIdx.x;
    for (int k = lane; k < T_ * T_; k += 64) tl[k] = trans[k];
    __syncthreads();

    if (bid < MAINW) {
        const bool isF = (bid < FWDW);
        const int widx = isF ? bid : bid - FWDW;
        const int j = widx >> 6;              // fwd: seg 0..14 ; bwd: seg j+1
        const int sg = widx & 63;
        const int h = lane >> 5;
        const int col = lane & 31;
        const int seq = sg * 32 + col;

        frag_u A1;
#pragma unroll
        for (int wd = 0; wd < 4; ++wd) {
            const int k0 = 8 * h + 2 * wd, k1 = k0 + 1;
            float e0 = 0.0f, e1 = 0.0f;
            if (col < 17) {
                e0 = isF ? __expf(tl[k0 * T_ + col]) : __expf(tl[col * T_ + k0]);
                e1 = isF ? __expf(tl[k1 * T_ + col]) : __expf(tl[col * T_ + k1]);
            }
            A1.u[wd] = pkbf(e0, e1);
        }
        float E16[9];
#pragma unroll
        for (int k = 0; k < 4; ++k) {
            const int r0 = 4 * h + k, r1 = 8 + 4 * h + k;
            E16[k]     = __expf(isF ? tl[16 * T_ + r0] : tl[r0 * T_ + 16]);
            E16[4 + k] = __expf(isF ? tl[16 * T_ + r1] : tl[r1 * T_ + 16]);
        }
        E16[8] = (h == 0) ? __expf(tl[16 * T_ + 16]) : 0.0f;

        v16f zacc;
#pragma unroll
        for (int r = 0; r < 16; ++r) zacc[r] = 0.0f;

        const float* ip = inputs + (size_t)seq * (S_ * T_);
        const int*   mp = mask + (size_t)seq * S_;

        float W0, W1, W2, W3, W4, W5, W6, W7, W8, w16, Z = 0.0f;
        f4u X0[8], X1[8]; float XS[8]; int4 XM0, XM1;
        f4u Y0[8], Y1[8]; float YS[8]; int4 YM0, YM1;

        int off;
        if (isF) {
            if (j == 0) {
                // F0: exact fwd from alpha0, steps t=1..31
                LOADK8(X0, X1, XS, XM0, XM1, 0);
                LOADK8(Y0, Y1, YS, YM0, YM1, 8);
                f4u s0 = *(const f4u*)(startt + 4 * h);
                f4u s1 = *(const f4u*)(startt + 8 + 4 * h);
                W0 = __expf(X0[0].x + s0.x); W1 = __expf(X0[0].y + s0.y);
                W2 = __expf(X0[0].z + s0.z); W3 = __expf(X0[0].w + s0.w);
                W4 = __expf(X1[0].x + s1.x); W5 = __expf(X1[0].y + s1.y);
                W6 = __expf(X1[0].z + s1.z); W7 = __expf(X1[0].w + s1.w);
                W8 = h ? 0.0f : __expf(XS[0] + startt[16]);
                W16SWAP();
                FSTEP(X0[1], X1[1], XS[1], XM0.y);
                FSTEP(X0[2], X1[2], XS[2], XM0.z);
                FSTEP(X0[3], X1[3], XS[3], XM0.w);
                RENORM();
                FSTEP(X0[4], X1[4], XS[4], XM1.x);
                FSTEP(X0[5], X1[5], XS[5], XM1.y);
                FSTEP(X0[6], X1[6], XS[6], XM1.z);
                FSTEP(X0[7], X1[7], XS[7], XM1.w);
                RENORM();
                LOADK8(X0, X1, XS, XM0, XM1, 16);
                FCH8(Y0, Y1, YS, YM0, YM1);               // t 8..15
                LOADK8(Y0, Y1, YS, YM0, YM1, 24);
                FCH8(X0, X1, XS, XM0, XM1);               // t 16..23
                FCH8(Y0, Y1, YS, YM0, YM1);               // t 24..31
            } else {
                // Fj: fwd from ones, steps t=32j..32j+31
                const int tb = LSEG * j;
                LOADK8(X0, X1, XS, XM0, XM1, tb);
                LOADK8(Y0, Y1, YS, YM0, YM1, tb + 8);
                W0=W1=W2=W3=W4=W5=W6=W7 = 1.0f;
                W8 = h ? 0.0f : 1.0f;
                W16SWAP();
                FCH8(X0, X1, XS, XM0, XM1);               // tb..tb+7
                LOADK8(X0, X1, XS, XM0, XM1, tb + 16);
                FCH8(Y0, Y1, YS, YM0, YM1);               // +8..15
                LOADK8(Y0, Y1, YS, YM0, YM1, tb + 24);
                FCH8(X0, X1, XS, XM0, XM1);               // +16..23
                FCH8(Y0, Y1, YS, YM0, YM1);               // +24..31
            }
            off = j * 18;
        } else {
            // Gjb: transpose run, steps t=32jb+31 .. 32jb (jb = j+1)
            const int jb = j + 1;
            const int tb = LSEG * jb;
            LOADK8(X0, X1, XS, XM0, XM1, tb + 24);
            LOADK8(Y0, Y1, YS, YM0, YM1, tb + 16);
            if (jb == NSEG - 1) {
                f4u e0 = *(const f4u*)(endt + 4 * h);
                f4u e1 = *(const f4u*)(endt + 8 + 4 * h);
                W0 = __expf(e0.x); W1 = __expf(e0.y);
                W2 = __expf(e0.z); W3 = __expf(e0.w);
                W4 = __expf(e1.x); W5 = __expf(e1.y);
                W6 = __expf(e1.z); W7 = __expf(e1.w);
                W8 = h ? 0.0f : __expf(endt[16]);
            } else {
                W0=W1=W2=W3=W4=W5=W6=W7 = 1.0f;
                W8 = h ? 0.0f : 1.0f;
            }
            W16SWAP();
            BCH8(X0, X1, XS, XM0, XM1);                   // tb+31..tb+24
            LOADK8(X0, X1, XS, XM0, XM1, tb + 8);
            BCH8(Y0, Y1, YS, YM0, YM1);                   // tb+23..tb+16
            LOADK8(Y0, Y1, YS, YM0, YM1, tb + 0);
            BCH8(X0, X1, XS, XM0, XM1);                   // tb+15..tb+8
            BCH8(Y0, Y1, YS, YM0, YM1);                   // tb+7..tb+0
            off = GB + (jb - 1) * 18;
        }

        float* rec = ws + (size_t)seq * RECN + off;
        rec[4*h+0] = W0; rec[4*h+1] = W1; rec[4*h+2] = W2; rec[4*h+3] = W3;
        rec[8+4*h+0] = W4; rec[8+4*h+1] = W5; rec[8+4*h+2] = W6; rec[8+4*h+3] = W7;
        if (h == 0) { rec[16] = W8; rec[17] = Z; }
    } else {
        helper_score(bid - MAINW, lane, tags, mask, inputs, startt, endt, tl, ws);
    }
}

// ---- combine: one thread per sequence; 8 block partials ----
__global__ __launch_bounds__(256) void crf_comb(const float* __restrict__ recs,
                                                float* __restrict__ partial)
{
    __shared__ float sm[256];
    const int tid = (int)threadIdx.x;
    const int s = (int)blockIdx.x * 256 + tid;

    float a = 0.0f;
    {
        const float* r = recs + (size_t)s * RECN;
        float zsum = r[17];               // ZF0
        float logn = 0.0f;
#pragma unroll
        for (int j = 1; j <= NSEG - 1; ++j) {
            const float* G = r + GB + (j - 1) * 18;
            const float* F = r + (j - 1) * 18;
            float dot = 0.0f;
#pragma unroll
            for (int i = 0; i < T_; ++i) dot = fmaf(G[i], F[i], dot);
            logn += __logf(dot);
            zsum += G[17];
        }
#pragma unroll
        for (int j = 1; j <= NSEG - 2; ++j) {
            const float* F = r + j * 18;
            float sf = 0.0f;
#pragma unroll
            for (int i = 0; i < T_; ++i) sf += F[i];
            logn -= __logf(sf);
        }
        a = r[540] - (logn + zsum);
    }
    sm[tid] = a;
    __syncthreads();
    for (int k = 128; k >= 1; k >>= 1) {
        if (tid < k) sm[tid] += sm[tid + k];
        __syncthreads();
    }
    if (tid == 0) partial[blockIdx.x] = sm[0];
}

__global__ __launch_bounds__(64) void crf_red(const float* __restrict__ partial,
                                              float* __restrict__ out)
{
    if (threadIdx.x == 0) {
        float s = 0.0f;
#pragma unroll
        for (int i = 0; i < 8; ++i) s += partial[i];
        out[0] = s;
    }
}

extern "C" void kernel_launch(void* const* d_in, const int* in_sizes, int n_in,
                              void* d_out, int out_size, void* d_ws, size_t ws_size,
                              hipStream_t stream)
{
    const float* inputs = (const float*)d_in[0];
    const int*   tags   = (const int*)d_in[1];
    const int*   mask   = (const int*)d_in[2];
    const float* trans  = (const float*)d_in[3];
    const float* startt = (const float*)d_in[4];
    const float* endt   = (const float*)d_in[5];
    float* out = (float*)d_out;
    float* ws  = (float*)d_ws;
    float* partial = ws + (size_t)B_ * RECN;

    crf_seg<<<MAINW + B_, 64, 0, stream>>>(inputs, tags, mask, trans,
                                           startt, endt, ws);
    crf_comb<<<B_ / 256, 256, 0, stream>>>(ws, partial);
    crf_red<<<1, 64, 0, stream>>>(partial, out);
}

// Round 16
// 55.358 us; speedup vs baseline: 1.3889x; 1.2707x over previous
//
#include <hip/hip_runtime.h>

#define B_ 2048
#define S_ 512
#define T_ 17
#define RECN 256
#define FWDW 448          // 7 segments x 64 waves (fwd F0..F6)
#define MAINW 896         // + 7 segments x 64 waves (bwd G1..G7)

typedef float v16f __attribute__((ext_vector_type(16)));
typedef short v8s  __attribute__((ext_vector_type(8)));
typedef float f4u  __attribute__((ext_vector_type(4), aligned(4)));

union frag_u { unsigned u[4]; v8s v; };

static __device__ inline unsigned pkbf(float lo, float hi) {
    unsigned r;
    asm("v_cvt_pk_bf16_f32 %0, %1, %2" : "=v"(r) : "v"(lo), "v"(hi));
    return r;
}

#define PACKB(S0,S1,S2,S3,S4,S5,S6,S7, BOUT) do {                            \
    unsigned P0_ = pkbf(S0, S1), P1_ = pkbf(S2, S3);                         \
    unsigned R0_ = pkbf(S4, S5), R1_ = pkbf(S6, S7);                         \
    auto s0_ = __builtin_amdgcn_permlane32_swap(P0_, R0_, false, false);     \
    auto s1_ = __builtin_amdgcn_permlane32_swap(P1_, R1_, false, false);     \
    BOUT.u[0] = s0_[0]; BOUT.u[1] = s1_[0];                                  \
    BOUT.u[2] = s0_[1]; BOUT.u[3] = s1_[1];                                  \
} while (0)

#define W16SWAP() do {                                                       \
    auto rw_ = __builtin_amdgcn_permlane32_swap(__float_as_uint(W8),         \
                                                __float_as_uint(W8),         \
                                                false, false);               \
    w16 = __uint_as_float(rw_[0]);                                           \
} while (0)

#define LOADK8(Q0, Q1, SS, MA, MB, T0_) do {                                 \
    const float* bp_ = ip + (size_t)(T0_) * T_;                              \
    _Pragma("unroll") for (int u_ = 0; u_ < 8; ++u_) {                       \
        Q0[u_] = *(const f4u*)(bp_ + u_ * T_ + 4 * h);                       \
        Q1[u_] = *(const f4u*)(bp_ + u_ * T_ + 8 + 4 * h);                   \
        SS[u_] = bp_[u_ * T_ + 16];                                          \
    }                                                                        \
    MA = *(const int4*)(mp + (T0_));                                         \
    MB = *(const int4*)(mp + (T0_) + 4);                                     \
} while (0)

#define FSTEP(Q0u, Q1u, Su, Mu) do {                                         \
    frag_u Bf_;                                                              \
    PACKB(W0,W1,W2,W3,W4,W5,W6,W7, Bf_);                                     \
    v16f acc_ = __builtin_amdgcn_mfma_f32_32x32x16_bf16(A1.v, Bf_.v, zacc,0,0,0); \
    float d0_=__expf((Q0u).x), d1_=__expf((Q0u).y);                          \
    float d2_=__expf((Q0u).z), d3_=__expf((Q0u).w);                          \
    float d4_=__expf((Q1u).x), d5_=__expf((Q1u).y);                          \
    float d6_=__expf((Q1u).z), d7_=__expf((Q1u).w);                          \
    float d8_=__expf(Su);                                                    \
    bool bm_ = (Mu) != 0;                                                    \
    float n0_ = fmaf(E16[0], w16, acc_[0]) * d0_;                            \
    float n1_ = fmaf(E16[1], w16, acc_[1]) * d1_;                            \
    float n2_ = fmaf(E16[2], w16, acc_[2]) * d2_;                            \
    float n3_ = fmaf(E16[3], w16, acc_[3]) * d3_;                            \
    float n4_ = fmaf(E16[4], w16, acc_[4]) * d4_;                            \
    float n5_ = fmaf(E16[5], w16, acc_[5]) * d5_;                            \
    float n6_ = fmaf(E16[6], w16, acc_[6]) * d6_;                            \
    float n7_ = fmaf(E16[7], w16, acc_[7]) * d7_;                            \
    float n8_ = fmaf(E16[8], w16, acc_[8]) * d8_;                            \
    W0=bm_?n0_:W0; W1=bm_?n1_:W1; W2=bm_?n2_:W2; W3=bm_?n3_:W3;              \
    W4=bm_?n4_:W4; W5=bm_?n5_:W5; W6=bm_?n6_:W6; W7=bm_?n7_:W7;              \
    W8=bm_?n8_:W8;                                                           \
    W16SWAP();                                                               \
} while (0)

#define BSTEP(Q0u, Q1u, Su, Mu) do {                                         \
    float d0_=__expf((Q0u).x), d1_=__expf((Q0u).y);                          \
    float d2_=__expf((Q0u).z), d3_=__expf((Q0u).w);                          \
    float d4_=__expf((Q1u).x), d5_=__expf((Q1u).y);                          \
    float d6_=__expf((Q1u).z), d7_=__expf((Q1u).w);                          \
    float d8_=__expf(Su);                                                    \
    float U16_ = w16 * d8_;                                                  \
    frag_u Bf_;                                                              \
    PACKB(W0*d0_, W1*d1_, W2*d2_, W3*d3_,                                    \
          W4*d4_, W5*d5_, W6*d6_, W7*d7_, Bf_);                              \
    v16f acc_ = __builtin_amdgcn_mfma_f32_32x32x16_bf16(A1.v, Bf_.v, zacc,0,0,0); \
    bool bm_ = (Mu) != 0;                                                    \
    float n0_ = fmaf(E16[0], U16_, acc_[0]);                                 \
    float n1_ = fmaf(E16[1], U16_, acc_[1]);                                 \
    float n2_ = fmaf(E16[2], U16_, acc_[2]);                                 \
    float n3_ = fmaf(E16[3], U16_, acc_[3]);                                 \
    float n4_ = fmaf(E16[4], U16_, acc_[4]);                                 \
    float n5_ = fmaf(E16[5], U16_, acc_[5]);                                 \
    float n6_ = fmaf(E16[6], U16_, acc_[6]);                                 \
    float n7_ = fmaf(E16[7], U16_, acc_[7]);                                 \
    float n8_ = fmaf(E16[8], U16_, acc_[8]);                                 \
    W0=bm_?n0_:W0; W1=bm_?n1_:W1; W2=bm_?n2_:W2; W3=bm_?n3_:W3;              \
    W4=bm_?n4_:W4; W5=bm_?n5_:W5; W6=bm_?n6_:W6; W7=bm_?n7_:W7;              \
    W8=bm_?n8_:W8;                                                           \
    W16SWAP();                                                               \
} while (0)

#define RENORM() do {                                                        \
    float M_ = fmaxf(fmaxf(fmaxf(W0,W1),fmaxf(W2,W3)),                       \
                     fmaxf(fmaxf(W4,W5),fmaxf(fmaxf(W6,W7),W8)));            \
    auto rm_ = __builtin_amdgcn_permlane32_swap(__float_as_uint(M_),         \
                                                __float_as_uint(M_),         \
                                                false, false);               \
    M_ = fmaxf(__uint_as_float(rm_[0]), __uint_as_float(rm_[1]));            \
    float r_ = 1.0f / M_;                                                    \
    Z += __logf(M_);                                                         \
    W0*=r_; W1*=r_; W2*=r_; W3*=r_; W4*=r_;                                  \
    W5*=r_; W6*=r_; W7*=r_; W8*=r_; w16*=r_;                                 \
} while (0)

#define FCH8(Q0a, Q1a, Sa, Ma, Mb) do {                                      \
    FSTEP(Q0a[0], Q1a[0], Sa[0], (Ma).x);                                    \
    FSTEP(Q0a[1], Q1a[1], Sa[1], (Ma).y);                                    \
    FSTEP(Q0a[2], Q1a[2], Sa[2], (Ma).z);                                    \
    FSTEP(Q0a[3], Q1a[3], Sa[3], (Ma).w);                                    \
    RENORM();                                                                \
    FSTEP(Q0a[4], Q1a[4], Sa[4], (Mb).x);                                    \
    FSTEP(Q0a[5], Q1a[5], Sa[5], (Mb).y);                                    \
    FSTEP(Q0a[6], Q1a[6], Sa[6], (Mb).z);                                    \
    FSTEP(Q0a[7], Q1a[7], Sa[7], (Mb).w);                                    \
    RENORM();                                                                \
} while (0)

#define BCH8(Q0a, Q1a, Sa, Ma, Mb) do {                                      \
    BSTEP(Q0a[7], Q1a[7], Sa[7], (Mb).w);                                    \
    BSTEP(Q0a[6], Q1a[6], Sa[6], (Mb).z);                                    \
    BSTEP(Q0a[5], Q1a[5], Sa[5], (Mb).y);                                    \
    BSTEP(Q0a[4], Q1a[4], Sa[4], (Mb).x);                                    \
    RENORM();                                                                \
    BSTEP(Q0a[3], Q1a[3], Sa[3], (Ma).w);                                    \
    BSTEP(Q0a[2], Q1a[2], Sa[2], (Ma).z);                                    \
    BSTEP(Q0a[1], Q1a[1], Sa[1], (Ma).y);                                    \
    BSTEP(Q0a[0], Q1a[0], Sa[0], (Ma).x);                                    \
    RENORM();                                                                \
} while (0)

static __device__ void helper_score(int s, int lane,
                                    const int* __restrict__ tags,
                                    const int* __restrict__ mask,
                                    const float* __restrict__ inputs,
                                    const float* __restrict__ startt,
                                    const float* __restrict__ endt,
                                    const float* tl, float* recs)
{
    const int* tp = tags + (size_t)s * S_;
    const int* mp = mask + (size_t)s * S_;
    const float* ib = inputs + (size_t)s * (S_ * T_);
    const int4* tp4 = (const int4*)tp;
    const int4* mp4 = (const int4*)mp;

    int4 t0 = tp4[2 * lane], t1 = tp4[2 * lane + 1];
    int4 m0 = mp4[2 * lane], m1 = mp4[2 * lane + 1];
    int tg[8] = {t0.x, t0.y, t0.z, t0.w, t1.x, t1.y, t1.z, t1.w};
    int mi[8] = {m0.x, m0.y, m0.z, m0.w, m1.x, m1.y, m1.z, m1.w};
    int tprev = (lane > 0) ? tp[8 * lane - 1] : 0;

    float e = 0.0f, tr = 0.0f;
    int ms = 0;
#pragma unroll
    for (int u = 0; u < 8; ++u) {
        int t = 8 * lane + u;
        float mf = (float)mi[u];
        float gate = (t <= S_ - 2) ? mf : 0.0f;
        e = fmaf(gate, ib[(size_t)t * T_ + tg[u]], e);
        int pt = (u == 0) ? tprev : tg[u - 1];
        float tv = tl[pt * T_ + tg[u]];
        tr = fmaf((t >= 1) ? mf : 0.0f, tv, tr);
        ms += mi[u];
    }
    for (int d = 1; d < 64; d <<= 1) {
        e  += __shfl_xor(e, d);
        tr += __shfl_xor(tr, d);
        ms += __shfl_xor(ms, d);
    }
    if (lane == 0) {
        int li = ms - 1; if (li < 0) li = 0;
        int lt = tp[li];
        float ml = (float)mp[S_ - 1];
        float lin = ib[(size_t)(S_ - 1) * T_ + lt];
        float sc = startt[tp[0]] + tr + e + endt[lt] + lin * ml;
        recs[(size_t)s * RECN + 252] = sc;
    }
}

__global__ __launch_bounds__(64) void crf_seg(
    const float* __restrict__ inputs, const int* __restrict__ tags,
    const int* __restrict__ mask, const float* __restrict__ trans,
    const float* __restrict__ startt, const float* __restrict__ endt,
    float* __restrict__ ws)
{
    __shared__ float tl[T_ * T_];
    const int lane = (int)threadIdx.x;
    const int bid = (int)blockIdx.x;
    for (int k = lane; k < T_ * T_; k += 64) tl[k] = trans[k];
    __syncthreads();

    if (bid < MAINW) {
        const bool isF = (bid < FWDW);
        const int widx = isF ? bid : bid - FWDW;
        const int j = widx >> 6;              // fwd: seg 0..6 ; bwd: seg j+1
        const int sg = widx & 63;
        const int h = lane >> 5;
        const int col = lane & 31;
        const int seq = sg * 32 + col;

        frag_u A1;
#pragma unroll
        for (int wd = 0; wd < 4; ++wd) {
            const int k0 = 8 * h + 2 * wd, k1 = k0 + 1;
            float e0 = 0.0f, e1 = 0.0f;
            if (col < 17) {
                e0 = isF ? __expf(tl[k0 * T_ + col]) : __expf(tl[col * T_ + k0]);
                e1 = isF ? __expf(tl[k1 * T_ + col]) : __expf(tl[col * T_ + k1]);
            }
            A1.u[wd] = pkbf(e0, e1);
        }
        float E16[9];
#pragma unroll
        for (int k = 0; k < 4; ++k) {
            const int r0 = 4 * h + k, r1 = 8 + 4 * h + k;
            E16[k]     = __expf(isF ? tl[16 * T_ + r0] : tl[r0 * T_ + 16]);
            E16[4 + k] = __expf(isF ? tl[16 * T_ + r1] : tl[r1 * T_ + 16]);
        }
        E16[8] = (h == 0) ? __expf(tl[16 * T_ + 16]) : 0.0f;

        v16f zacc;
#pragma unroll
        for (int r = 0; r < 16; ++r) zacc[r] = 0.0f;

        const float* ip = inputs + (size_t)seq * (S_ * T_);
        const int*   mp = mask + (size_t)seq * S_;

        float W0, W1, W2, W3, W4, W5, W6, W7, W8, w16, Z = 0.0f;
        f4u X0[8], X1[8]; float XS[8]; int4 XM0, XM1;
        f4u Y0[8], Y1[8]; float YS[8]; int4 YM0, YM1;

        int off;
        if (isF) {
            if (j == 0) {
                // F0: exact fwd from alpha0, steps t=1..63
                LOADK8(X0, X1, XS, XM0, XM1, 0);
                LOADK8(Y0, Y1, YS, YM0, YM1, 8);
                f4u s0 = *(const f4u*)(startt + 4 * h);
                f4u s1 = *(const f4u*)(startt + 8 + 4 * h);
                W0 = __expf(X0[0].x + s0.x); W1 = __expf(X0[0].y + s0.y);
                W2 = __expf(X0[0].z + s0.z); W3 = __expf(X0[0].w + s0.w);
                W4 = __expf(X1[0].x + s1.x); W5 = __expf(X1[0].y + s1.y);
                W6 = __expf(X1[0].z + s1.z); W7 = __expf(X1[0].w + s1.w);
                W8 = h ? 0.0f : __expf(XS[0] + startt[16]);
                W16SWAP();
                FSTEP(X0[1], X1[1], XS[1], XM0.y);
                FSTEP(X0[2], X1[2], XS[2], XM0.z);
                FSTEP(X0[3], X1[3], XS[3], XM0.w);
                RENORM();
                FSTEP(X0[4], X1[4], XS[4], XM1.x);
                FSTEP(X0[5], X1[5], XS[5], XM1.y);
                FSTEP(X0[6], X1[6], XS[6], XM1.z);
                FSTEP(X0[7], X1[7], XS[7], XM1.w);
                RENORM();
                for (int c = 0; c < 3; ++c) {
                    LOADK8(X0, X1, XS, XM0, XM1, 16 + 16 * c);
                    FCH8(Y0, Y1, YS, YM0, YM1);
                    LOADK8(Y0, Y1, YS, YM0, YM1, 24 + 16 * c);
                    FCH8(X0, X1, XS, XM0, XM1);
                }
                FCH8(Y0, Y1, YS, YM0, YM1);
            } else {
                // Fj: fwd from ones, steps t=64j..64j+63
                const int tb = 64 * j;
                LOADK8(X0, X1, XS, XM0, XM1, tb);
                LOADK8(Y0, Y1, YS, YM0, YM1, tb + 8);
                W0=W1=W2=W3=W4=W5=W6=W7 = 1.0f;
                W8 = h ? 0.0f : 1.0f;
                W16SWAP();
                for (int c = 0; c < 3; ++c) {
                    FCH8(X0, X1, XS, XM0, XM1);
                    LOADK8(X0, X1, XS, XM0, XM1, tb + 16 + 16 * c);
                    FCH8(Y0, Y1, YS, YM0, YM1);
                    LOADK8(Y0, Y1, YS, YM0, YM1, tb + 24 + 16 * c);
                }
                FCH8(X0, X1, XS, XM0, XM1);
                FCH8(Y0, Y1, YS, YM0, YM1);
            }
            off = j * 18;
        } else {
            // Gjb: transpose run, steps t=64jb+63 .. 64jb (jb = j+1)
            const int jb = j + 1;
            const int tb = 64 * jb;
            LOADK8(X0, X1, XS, XM0, XM1, tb + 56);
            LOADK8(Y0, Y1, YS, YM0, YM1, tb + 48);
            if (jb == 7) {
                f4u e0 = *(const f4u*)(endt + 4 * h);
                f4u e1 = *(const f4u*)(endt + 8 + 4 * h);
                W0 = __expf(e0.x); W1 = __expf(e0.y);
                W2 = __expf(e0.z); W3 = __expf(e0.w);
                W4 = __expf(e1.x); W5 = __expf(e1.y);
                W6 = __expf(e1.z); W7 = __expf(e1.w);
                W8 = h ? 0.0f : __expf(endt[16]);
            } else {
                W0=W1=W2=W3=W4=W5=W6=W7 = 1.0f;
                W8 = h ? 0.0f : 1.0f;
            }
            W16SWAP();
            for (int c = 0; c < 3; ++c) {
                BCH8(X0, X1, XS, XM0, XM1);
                LOADK8(X0, X1, XS, XM0, XM1, tb + 40 - 16 * c);
                BCH8(Y0, Y1, YS, YM0, YM1);
                LOADK8(Y0, Y1, YS, YM0, YM1, tb + 32 - 16 * c);
            }
            BCH8(X0, X1, XS, XM0, XM1);
            BCH8(Y0, Y1, YS, YM0, YM1);
            off = 126 + (jb - 1) * 18;
        }

        float* rec = ws + (size_t)seq * RECN + off;
        rec[4*h+0] = W0; rec[4*h+1] = W1; rec[4*h+2] = W2; rec[4*h+3] = W3;
        rec[8+4*h+0] = W4; rec[8+4*h+1] = W5; rec[8+4*h+2] = W6; rec[8+4*h+3] = W7;
        if (h == 0) { rec[16] = W8; rec[17] = Z; }
    } else {
        helper_score(bid - MAINW, lane, tags, mask, inputs, startt, endt, tl, ws);
    }
}

// ---- combine: one THREAD per sequence, 8 blocks; per-block partial sums ----
__global__ __launch_bounds__(256) void crf_comb(const float* __restrict__ recs,
                                                float* __restrict__ partial)
{
    __shared__ float sm[256];
    const int tid = (int)threadIdx.x;
    const int s = (int)blockIdx.x * 256 + tid;

    float a = 0.0f;
    {
        const float* r = recs + (size_t)s * RECN;
        float zsum = r[17];               // ZF0
        float logn = 0.0f;
#pragma unroll
        for (int j = 1; j <= 7; ++j) {
            const float* G = r + 126 + (j - 1) * 18;
            const float* F = r + (j - 1) * 18;
            float dot = 0.0f;
#pragma unroll
            for (int i = 0; i < T_; ++i) dot = fmaf(G[i], F[i], dot);
            logn += __logf(dot);
            zsum += G[17];
        }
#pragma unroll
        for (int j = 1; j <= 6; ++j) {
            const float* F = r + j * 18;
            float sf = 0.0f;
#pragma unroll
            for (int i = 0; i < T_; ++i) sf += F[i];
            logn -= __logf(sf);
        }
        a = r[252] - (logn + zsum);
    }
    sm[tid] = a;
    __syncthreads();
    for (int k = 128; k >= 1; k >>= 1) {
        if (tid < k) sm[tid] += sm[tid + k];
        __syncthreads();
    }
    if (tid == 0) partial[blockIdx.x] = sm[0];
}

__global__ __launch_bounds__(64) void crf_red(const float* __restrict__ partial,
                                              float* __restrict__ out)
{
    if (threadIdx.x == 0) {
        float s = 0.0f;
#pragma unroll
        for (int i = 0; i < 8; ++i) s += partial[i];
        out[0] = s;
    }
}

extern "C" void kernel_launch(void* const* d_in, const int* in_sizes, int n_in,
                              void* d_out, int out_size, void* d_ws, size_t ws_size,
                              hipStream_t stream)
{
    const float* inputs = (const float*)d_in[0];
    const int*   tags   = (const int*)d_in[1];
    const int*   mask   = (const int*)d_in[2];
    const float* trans  = (const float*)d_in[3];
    const float* startt = (const float*)d_in[4];
    const float* endt   = (const float*)d_in[5];
    float* out = (float*)d_out;
    float* ws  = (float*)d_ws;
    float* partial = ws + (size_t)B_ * RECN;

    crf_seg<<<MAINW + B_, 64, 0, stream>>>(inputs, tags, mask, trans,
                                           startt, endt, ws);
    crf_comb<<<B_ / 256, 256, 0, stream>>>(ws, partial);
    crf_red<<<1, 64, 0, stream>>>(partial, out);
}